// Round 1
// baseline (982.038 us; speedup 1.0000x reference)
//
#include <hip/hip_runtime.h>
#include <math.h>

// Problem dims (fixed by reference)
#define BB 2048
#define TT 90
#define AA 4
#define DD 256
#define HH 10
#define OO 2
// tasks = BB*TT = 184320 ; 16 tasks per wave -> 11520 waves -> 2880 blocks of 256

// ---------------------------------------------------------------------------
// Kernel 1: sn_in[b,t,h] = (sum_a x[b,t,a,:]*w_ant[a] + b_ant) . w_hid[h,:] + b_hid[h]
// One wave handles 16 consecutive flattened (b,t) tasks.
// lane = (tq = lane>>2, c = lane&3); lane covers d in {c*4 + 16*j, j=0..15}
// => each wave load instr reads 16 groups x 64B contiguous = fully coalesced 1KB.
// All accumulation in f64 to match the numpy (f64) reference bit-tightly
// (spike threshold is a discontinuity; f32 reduction-order noise can flip spikes).
// ---------------------------------------------------------------------------
template <typename ST>
__global__ __launch_bounds__(256) void k1_fuse(
    const float* __restrict__ x,
    const float* __restrict__ w_ant,
    const float* __restrict__ b_ant,
    const float* __restrict__ w_hid,
    const float* __restrict__ b_hid,
    ST* __restrict__ sn)
{
    __shared__ float lds_whid[HH * DD];   // 10 KB

    // cooperative stage of w_hid into LDS (640 float4)
    for (int i = threadIdx.x; i < (HH * DD) / 4; i += blockDim.x) {
        reinterpret_cast<float4*>(lds_whid)[i] =
            reinterpret_cast<const float4*>(w_hid)[i];
    }
    __syncthreads();

    const int wave = (blockIdx.x * blockDim.x + threadIdx.x) >> 6;
    const int lane = threadIdx.x & 63;
    const int tq   = lane >> 2;      // which of the 16 tasks in this tile
    const int c    = lane & 3;       // d-chunk id within task
    const size_t tau = (size_t)wave * 16 + tq;   // flattened (b*TT + t), < 184320

    const double wa0 = (double)w_ant[0];
    const double wa1 = (double)w_ant[1];
    const double wa2 = (double)w_ant[2];
    const double wa3 = (double)w_ant[3];
    const double ba  = (double)b_ant[0];

    double p[HH];
#pragma unroll
    for (int h = 0; h < HH; ++h) p[h] = 0.0;

    const float* xb = x + tau * (size_t)(AA * DD);

#pragma unroll 4
    for (int dd = 0; dd < 16; ++dd) {
        const int off = dd * 16 + c * 4;
        const float4 x0 = *reinterpret_cast<const float4*>(xb + 0 * DD + off);
        const float4 x1 = *reinterpret_cast<const float4*>(xb + 1 * DD + off);
        const float4 x2 = *reinterpret_cast<const float4*>(xb + 2 * DD + off);
        const float4 x3 = *reinterpret_cast<const float4*>(xb + 3 * DD + off);

        const double f0 = ba + wa0 * (double)x0.x + wa1 * (double)x1.x
                             + wa2 * (double)x2.x + wa3 * (double)x3.x;
        const double f1 = ba + wa0 * (double)x0.y + wa1 * (double)x1.y
                             + wa2 * (double)x2.y + wa3 * (double)x3.y;
        const double f2 = ba + wa0 * (double)x0.z + wa1 * (double)x1.z
                             + wa2 * (double)x2.z + wa3 * (double)x3.z;
        const double f3 = ba + wa0 * (double)x0.w + wa1 * (double)x1.w
                             + wa2 * (double)x2.w + wa3 * (double)x3.w;

#pragma unroll
        for (int h = 0; h < HH; ++h) {
            const float4 wh =
                *reinterpret_cast<const float4*>(&lds_whid[h * DD + off]);
            p[h] += f0 * (double)wh.x + f1 * (double)wh.y +
                    f2 * (double)wh.z + f3 * (double)wh.w;
        }
    }

    // reduce across the 4 d-chunk lanes (xor 1, 2) — all 4 lanes end with sum
#pragma unroll
    for (int h = 0; h < HH; ++h) {
        p[h] += __shfl_xor(p[h], 1, 64);
        p[h] += __shfl_xor(p[h], 2, 64);
    }

    // lane c writes h = c, c+4, (c<2: c+8). Select with compile-time indices
    // (runtime-indexed register arrays would spill to scratch).
    double v0 = 0.0, v1 = 0.0, v2 = 0.0;
#pragma unroll
    for (int h = 0; h < HH; ++h) {
        if (h == c)     v0 = p[h];
        if (h == c + 4) v1 = p[h];
        if (h == c + 8) v2 = p[h];
    }
    const double bh0 = (double)b_hid[c];
    const double bh1 = (double)b_hid[c + 4];

    ST* dst = sn + tau * HH;
    dst[c]     = (ST)(v0 + bh0);
    dst[c + 4] = (ST)(v1 + bh1);
    if (c < 2) {
        const double bh2 = (double)b_hid[c + 8];
        dst[c + 8] = (ST)(v2 + bh2);
    }
}

// ---------------------------------------------------------------------------
// Kernel 2: Leaky scan over T (independent per (b,h)) + time fuse + output
// linear + softmax. Thread = (b,h); 25 b's per 256-thread block; chunked
// loads (10 in flight) to hide HBM latency on the sequential scan.
// ---------------------------------------------------------------------------
template <typename ST>
__global__ __launch_bounds__(256) void k2_scan(
    const ST* __restrict__ sn,
    const float* __restrict__ w_time,
    const float* __restrict__ b_time,
    const float* __restrict__ w_out,
    const float* __restrict__ b_out,
    float* __restrict__ out)
{
    __shared__ double lds_wt[TT];
    __shared__ double lds_ft[25][HH];

    for (int i = threadIdx.x; i < TT; i += blockDim.x)
        lds_wt[i] = (double)w_time[i];
    __syncthreads();

    const int tid  = threadIdx.x;
    const int bloc = tid / HH;           // 0..24 for tid < 250
    const int h    = tid % HH;
    const int bb   = blockIdx.x * 25 + bloc;
    const bool active = (tid < 250) && (bb < BB);

    double mem = 0.0;
    double acc = (double)b_time[0];

    if (active) {
        const ST* src = sn + (size_t)bb * (TT * HH) + h;
#pragma unroll
        for (int tc = 0; tc < TT; tc += 10) {
            double v[10];
#pragma unroll
            for (int j = 0; j < 10; ++j)
                v[j] = (double)src[(size_t)(tc + j) * HH];
#pragma unroll
            for (int j = 0; j < 10; ++j) {
                // reset from PREVIOUS mem (zero-reset mechanism)
                const double keep = (mem > 1.0) ? 0.0 : 1.0;
                mem = (0.95 * mem + v[j]) * keep;
                if (mem > 1.0) acc += lds_wt[tc + j];   // spike * w_time[t]
            }
        }
    }

    if (active) lds_ft[bloc][h] = acc;
    __syncthreads();

    if (tid < 25) {
        const int b2 = blockIdx.x * 25 + tid;
        if (b2 < BB) {
            double o0 = (double)b_out[0];
            double o1 = (double)b_out[1];
#pragma unroll
            for (int h2 = 0; h2 < HH; ++h2) {
                const double f = lds_ft[tid][h2];
                o0 += f * (double)w_out[h2];
                o1 += f * (double)w_out[HH + h2];
            }
            const double m  = fmax(o0, o1);
            const double e0 = exp(o0 - m);
            const double e1 = exp(o1 - m);
            const double s  = e0 + e1;
            out[b2 * 2 + 0] = (float)(e0 / s);
            out[b2 * 2 + 1] = (float)(e1 / s);
        }
    }
}

// ---------------------------------------------------------------------------
extern "C" void kernel_launch(void* const* d_in, const int* in_sizes, int n_in,
                              void* d_out, int out_size, void* d_ws, size_t ws_size,
                              hipStream_t stream)
{
    const float* x      = (const float*)d_in[0];
    const float* w_ant  = (const float*)d_in[1];
    const float* b_ant  = (const float*)d_in[2];
    const float* w_hid  = (const float*)d_in[3];
    const float* b_hid  = (const float*)d_in[4];
    const float* w_time = (const float*)d_in[5];
    const float* b_time = (const float*)d_in[6];
    const float* w_out  = (const float*)d_in[7];
    const float* b_out  = (const float*)d_in[8];
    float* out = (float*)d_out;

    const int k1_blocks = (BB * TT) / 16 / 4;        // 2880 (exact)
    const int k2_blocks = (BB + 24) / 25;            // 82

    if (ws_size >= (size_t)BB * TT * HH * sizeof(double)) {
        double* sn = (double*)d_ws;
        k1_fuse<double><<<k1_blocks, 256, 0, stream>>>(x, w_ant, b_ant, w_hid, b_hid, sn);
        k2_scan<double><<<k2_blocks, 256, 0, stream>>>(sn, w_time, b_time, w_out, b_out, out);
    } else {
        float* sn = (float*)d_ws;
        k1_fuse<float><<<k1_blocks, 256, 0, stream>>>(x, w_ant, b_ant, w_hid, b_hid, sn);
        k2_scan<float><<<k2_blocks, 256, 0, stream>>>(sn, w_time, b_time, w_out, b_out, out);
    }
}